// Round 2
// baseline (10045.988 us; speedup 1.0000x reference)
//
#include <hip/hip_runtime.h>
#include <math.h>

#define SEQ 512
#define BATCH 8
#define HID 768
#define G4 3072           // 4*HID
#define CHUNK 128
#define NEGV (-1000000000.0f)

__device__ __forceinline__ float sigm(float x) { return 1.0f / (1.0f + expf(-x)); }

__device__ __forceinline__ float wred(float x) {
#pragma unroll
  for (int off = 32; off > 0; off >>= 1) x += __shfl_xor(x, off, 64);
  return x;
}

// ---------------------------------------------------------------- init zeros
// zeros hbuf (both parities) and the barrier counters. hf/hr are fully
// overwritten by k_rec1 so they need no init.
__global__ void k_init(float* __restrict__ hbuf, int* __restrict__ bar) {
  int i = blockIdx.x * blockDim.x + threadIdx.x;
  if (i < 2 * 2 * BATCH * HID) hbuf[i] = 0.0f;   // [par][dir][b][HID]
  if (i < 1024) bar[i] = 0;                      // [dir][s]
}

// ------------------------------------------- L1 input projection, one chunk
__global__ __launch_bounds__(256) void k_proj1(
    const float* __restrict__ emb,
    const float* __restrict__ w_f, const float* __restrict__ b_f,
    const float* __restrict__ w_r, const float* __restrict__ b_r,
    float* __restrict__ xs_f, float* __restrict__ xs_r, int chunk) {
  __shared__ float As[16][132];
  __shared__ float Bs[16][132];
  const int tid = threadIdx.x;
  const int bn0 = blockIdx.x * 128;       // col tile over 3072
  const int bb  = blockIdx.y;             // batch
  const int dir = blockIdx.z;
  const float* W    = dir ? w_r : w_f;
  const float* bias = dir ? b_r : b_f;
  float* xs = dir ? xs_r : xs_f;

  float acc[8][8];
#pragma unroll
  for (int i = 0; i < 8; i++)
#pragma unroll
    for (int j = 0; j < 8; j++) acc[i][j] = 0.0f;

  const int mload = tid & 127;
  const int kq0   = tid >> 7;
  const int tglob = dir ? (SEQ - 1 - (chunk * CHUNK + mload)) : (chunk * CHUNK + mload);
  const float* arow = emb + (size_t)(bb * SEQ + tglob) * HID;
  const float* brow = W + (size_t)(bn0 + mload) * HID;
  const int tm = tid & 15, tn = tid >> 4;

  for (int kt = 0; kt < HID; kt += 16) {
#pragma unroll
    for (int rep = 0; rep < 2; rep++) {
      int kq = kq0 + rep * 2;
      float4 a = *(const float4*)(arow + kt + kq * 4);
      As[kq * 4 + 0][mload] = a.x; As[kq * 4 + 1][mload] = a.y;
      As[kq * 4 + 2][mload] = a.z; As[kq * 4 + 3][mload] = a.w;
      float4 b = *(const float4*)(brow + kt + kq * 4);
      Bs[kq * 4 + 0][mload] = b.x; Bs[kq * 4 + 1][mload] = b.y;
      Bs[kq * 4 + 2][mload] = b.z; Bs[kq * 4 + 3][mload] = b.w;
    }
    __syncthreads();
#pragma unroll
    for (int k = 0; k < 16; k++) {
      float4 a0 = *(const float4*)&As[k][tm * 8];
      float4 a1 = *(const float4*)&As[k][tm * 8 + 4];
      float4 b0 = *(const float4*)&Bs[k][tn * 8];
      float4 b1 = *(const float4*)&Bs[k][tn * 8 + 4];
      float av[8] = {a0.x, a0.y, a0.z, a0.w, a1.x, a1.y, a1.z, a1.w};
      float bv[8] = {b0.x, b0.y, b0.z, b0.w, b1.x, b1.y, b1.z, b1.w};
#pragma unroll
      for (int i = 0; i < 8; i++)
#pragma unroll
        for (int j = 0; j < 8; j++) acc[i][j] += av[i] * bv[j];
    }
    __syncthreads();
  }
#pragma unroll
  for (int i = 0; i < 8; i++) {
    int row = tm * 8 + i;
    size_t base = (size_t)(bb * CHUNK + row) * G4 + bn0 + tn * 8;
#pragma unroll
    for (int j = 0; j < 8; j++) xs[base + j] = acc[i][j] + bias[bn0 + tn * 8 + j];
  }
}

// ---------------------------------------- L1 recurrence: persistent kernel
// 256 blocks x 384 threads, LDS ~100KB -> exactly 1 block/CU -> all resident.
// Block (dir, jb) owns hidden units [jb*6, jb*6+6) = 24 gate rows, weights
// cached in LDS for the whole 128-step chunk. Per-dir flag barrier per step.
__global__ __launch_bounds__(384) void k_rec1(
    const float* __restrict__ whh_f, const float* __restrict__ whh_r,
    const float* __restrict__ xs_f, const float* __restrict__ xs_r,
    float* __restrict__ hbuf, float* __restrict__ cbuf, int* __restrict__ bar,
    float* __restrict__ hf, float* __restrict__ hr, int t0, int init) {
  __shared__ float wlds[24 * 772];   // row stride 772: 4-bank offset/row -> conflict-free
  __shared__ float hlds[8 * 772];
  __shared__ float psl[2 * 192];
  const int tid = threadIdx.x;
  const int bid = blockIdx.x;
  const int dir = bid >> 7;
  const int jb  = bid & 127;
  const int J0  = jb * 6;
  const float* whh = dir ? whh_r : whh_f;
  const float* xs  = dir ? xs_r  : xs_f;
  float* harr = dir ? hr : hf;

  // stage W_hh slice into LDS once (24 rows x 768)
  for (int i = tid; i < 24 * 192; i += 384) {
    int lr = i / 192, q = i - lr * 192;
    int rg = (lr / 6) * HID + J0 + (lr % 6);
    float4 w = ((const float4*)whh)[(size_t)rg * 192 + q];
    *(float4*)&wlds[lr * 772 + q * 4] = w;
  }

  const int half = tid / 192;             // k-split
  const int out  = tid - half * 192;      // (row,b) output id
  const int r  = out >> 3, bb = out & 7;
  const int gg = r / 6, jj = r - gg * 6;
  const int rg = gg * HID + J0 + jj;

  float c = 0.0f;
  if (init == 0 && tid < 48) c = cbuf[bid * 48 + tid];
  __syncthreads();

  for (int stp = 0; stp < CHUNK; stp++) {
    const int s = t0 + stp;
    const int par = s & 1;
    // xs load issued early (independent of barrier/h)
    float xsv = (half == 0) ? xs[(size_t)(bb * CHUNK + stp) * G4 + rg] : 0.0f;
    // h_{s-1} -> LDS
    {
      const float* hb = hbuf + (size_t)(par * 2 + dir) * BATCH * HID;
      for (int q2 = tid; q2 < 1536; q2 += 384) {
        int b2 = q2 / 192;
        int k2 = (q2 - b2 * 192) * 4;
        float4 h4 = *(const float4*)(hb + b2 * HID + k2);
        *(float4*)&hlds[b2 * 772 + k2] = h4;
      }
    }
    __syncthreads();
    // 24x8 dots of length 768, k-split by 2
    {
      float acc = 0.0f;
      const float4* wp = (const float4*)(wlds + r * 772) + half * 96;
      const float4* hp = (const float4*)(hlds + bb * 772) + half * 96;
#pragma unroll 8
      for (int q2 = 0; q2 < 96; q2++) {
        float4 w = wp[q2], h4 = hp[q2];
        acc += w.x * h4.x + w.y * h4.y + w.z * h4.z + w.w * h4.w;
      }
      psl[half * 192 + out] = acc + xsv;
    }
    __syncthreads();
    // c/h update for 6 j x 8 b
    if (tid < 48) {
      int jj2 = tid >> 3, b2 = tid & 7;
      int o0 = jj2 * 8 + b2;
      float iv = psl[o0]        + psl[192 + o0];
      float fv = psl[48 + o0]   + psl[192 + 48 + o0];
      float gv = psl[96 + o0]   + psl[192 + 96 + o0];
      float ov = psl[144 + o0]  + psl[192 + 144 + o0];
      c = sigm(fv) * c + sigm(iv) * tanhf(gv);
      float h = sigm(ov) * tanhf(c);
      int t = dir ? (SEQ - 1 - s) : s;
      int j = J0 + jj2;
      hbuf[(size_t)((par ^ 1) * 2 + dir) * BATCH * HID + b2 * HID + j] = h;
      harr[(size_t)(b2 * SEQ + t) * HID + j] = h;
    }
    if (stp == CHUNK - 1) break;
    __syncthreads();
    // per-dir grid barrier: release h writes, arrive, spin, acquire
    if (tid == 0) {
      __threadfence();
      atomicAdd(&bar[dir * SEQ + s], 1);
      while (__hip_atomic_load(&bar[dir * SEQ + s], __ATOMIC_RELAXED,
                               __HIP_MEMORY_SCOPE_AGENT) < 128) {
        __builtin_amdgcn_s_sleep(1);
      }
      __threadfence();   // acquire: invalidate L1/L2 so hbuf reads are fresh
    }
    __syncthreads();
  }
  if (tid < 48) cbuf[bid * 48 + tid] = c;
}

// ----------------------------------------------------------- hs = hf + hr
__global__ void k_sum(float* __restrict__ hf, const float* __restrict__ hr) {
  int i = blockIdx.x * 256 + threadIdx.x;
  float4 a = ((const float4*)hf)[i];
  float4 b = ((const float4*)hr)[i];
  a.x += b.x; a.y += b.y; a.z += b.z; a.w += b.w;
  ((float4*)hf)[i] = a;
}

// --------------------------------------------------------- windowed attention
__global__ __launch_bounds__(64) void k_attn(
    const float* __restrict__ hs, const float* __restrict__ attn_w,
    const float* __restrict__ attn_b, float* __restrict__ att) {
  const int l = threadIdx.x;
  const int s = blockIdx.x, b = blockIdx.y;
  const float* hrow = hs + (size_t)(b * SEQ + s) * HID;
  float v[12];
  float u1p = 0.0f;
#pragma unroll
  for (int j = 0; j < 12; j++) {
    int d = l + 64 * j;
    float x = hrow[d];
    u1p += x * attn_w[d];
    v[j] = attn_w[HID + d] + x * attn_w[2 * HID + d];
  }
  float u1 = wred(u1p) + attn_b[0];
  float sc[21];
  for (int o = 0; o < 21; o++) {
    int s2 = s + o - 10;
    if (s2 >= 0 && s2 < SEQ) {
      const float* h2 = hs + (size_t)(b * SEQ + s2) * HID;
      float p = 0.0f;
#pragma unroll
      for (int j = 0; j < 12; j++) p += h2[l + 64 * j] * v[j];
      sc[o] = wred(p) + u1;
    } else {
      sc[o] = NEGV;
    }
  }
  float m = sc[0];
#pragma unroll
  for (int o = 1; o < 21; o++) m = fmaxf(m, sc[o]);
  float sum = 0.0f;
#pragma unroll
  for (int o = 0; o < 21; o++) { sc[o] = expf(sc[o] - m); sum += sc[o]; }
  float inv = 1.0f / sum;
  float acc[12];
#pragma unroll
  for (int j = 0; j < 12; j++) acc[j] = 0.0f;
  for (int o = 0; o < 21; o++) {
    int s2 = s + o - 10;
    if (s2 < 0 || s2 >= SEQ) continue;
    float a = sc[o] * inv;
    const float* h2 = hs + (size_t)(b * SEQ + s2) * HID;
#pragma unroll
    for (int j = 0; j < 12; j++) acc[j] += a * h2[l + 64 * j];
  }
  float* orow = att + (size_t)(b * SEQ + s) * HID;
#pragma unroll
  for (int j = 0; j < 12; j++) orow[l + 64 * j] = acc[j];
}

// -------------------------------------------------------- L2 input projection
__global__ __launch_bounds__(256) void k_proj2(
    const float* __restrict__ hs, const float* __restrict__ att,
    const float* __restrict__ w2f, const float* __restrict__ b2f,
    const float* __restrict__ w2r, const float* __restrict__ b2r,
    float* __restrict__ xs2) {
  __shared__ __align__(16) float x2[2 * HID];
  __shared__ float part[32][9];
  const int tid = threadIdx.x;
  const int s = blockIdx.x, b = blockIdx.y;
  size_t base = (size_t)(b * SEQ + s) * HID;
  for (int i = tid; i < 2 * HID; i += 256)
    x2[i] = (i < HID) ? hs[base + i] : att[base + i - HID];
  __syncthreads();
  const int gid = tid & 31, pp = tid >> 5;
  const int d = gid >> 4, g = gid & 15;
  const float4* w4 = (const float4*)((d ? w2r : w2f) + (size_t)g * (2 * HID));
  const float4* x4 = (const float4*)x2;
  float p = 0.0f;
  for (int e = pp * 48; e < pp * 48 + 48; e++) {
    float4 xv = x4[e];
    float4 wv = w4[e];
    p += xv.x * wv.x + xv.y * wv.y + xv.z * wv.z + xv.w * wv.w;
  }
  part[gid][pp] = p;
  __syncthreads();
  if (tid < 32) {
    float sumv = (d ? b2r : b2f)[g];
#pragma unroll
    for (int q = 0; q < 8; q++) sumv += part[gid][q];
    xs2[(size_t)((d * BATCH + b) * SEQ + s) * 16 + g] = sumv;
  }
}

// ------------------------------------------------------------- L2 recurrence
__global__ __launch_bounds__(256) void k_rec2(
    const float* __restrict__ xs2,
    const float* __restrict__ whh_f, const float* __restrict__ whh_r,
    float* __restrict__ h2) {
  __shared__ float hsh[2 * BATCH * 4];
  __shared__ float gsh[2 * BATCH * 16];
  const int tid = threadIdx.x;
  const int d = tid >> 7, b = (tid >> 4) & 7, g = tid & 15;
  const float* whh = (d ? whh_r : whh_f) + g * 4;
  const float w0 = whh[0], w1 = whh[1], w2 = whh[2], w3 = whh[3];
  const int hb = d * BATCH + b;
  if (g < 4) hsh[hb * 4 + g] = 0.0f;
  float c = 0.0f;
  __syncthreads();
  const float* xrow = xs2 + (size_t)hb * SEQ * 16 + g;
  for (int st = 0; st < SEQ; st++) {
    int t = d ? (SEQ - 1 - st) : st;
    float gv = xrow[t * 16] + w0 * hsh[hb * 4 + 0] + w1 * hsh[hb * 4 + 1] +
               w2 * hsh[hb * 4 + 2] + w3 * hsh[hb * 4 + 3];
    gsh[hb * 16 + g] = gv;
    __syncthreads();
    if (g < 4) {
      float iv = gsh[hb * 16 + g];
      float fv = gsh[hb * 16 + 4 + g];
      float gq = gsh[hb * 16 + 8 + g];
      float ov = gsh[hb * 16 + 12 + g];
      c = sigm(fv) * c + sigm(iv) * tanhf(gq);
      float h = sigm(ov) * tanhf(c);
      hsh[hb * 4 + g] = h;
      h2[((size_t)hb * SEQ + t) * 4 + g] = h;
    }
    __syncthreads();
  }
}

// ------------------------------------------------------------------ em = f+r
__global__ void k_em(const float* __restrict__ h2, float* __restrict__ out) {
  int i = blockIdx.x * 256 + threadIdx.x;
  if (i < BATCH * SEQ * 4) out[BATCH * SEQ + i] = h2[i] + h2[BATCH * SEQ * 4 + i];
}

// ------------------------------------------------------------------- viterbi
__global__ __launch_bounds__(32) void k_viterbi(
    float* __restrict__ out, const float* __restrict__ start,
    const float* __restrict__ endw, const float* __restrict__ trans) {
  __shared__ unsigned char bp[SEQ - 1][32];
  const int l = threadIdx.x;
  const int b = l >> 2, j = l & 3;
  const float* em = out + BATCH * SEQ;
  const float tr0 = trans[0 * 4 + j], tr1 = trans[1 * 4 + j];
  const float tr2 = trans[2 * 4 + j], tr3 = trans[3 * 4 + j];
  float score = start[j] + em[((size_t)b * SEQ + 0) * 4 + j];
  for (int t = 1; t < SEQ; t++) {
    float s0 = __shfl(score, b * 4 + 0, 64);
    float s1 = __shfl(score, b * 4 + 1, 64);
    float s2 = __shfl(score, b * 4 + 2, 64);
    float s3 = __shfl(score, b * 4 + 3, 64);
    float v0 = s0 + tr0, v1 = s1 + tr1, v2 = s2 + tr2, v3 = s3 + tr3;
    float best = v0; int arg = 0;
    if (v1 > best) { best = v1; arg = 1; }
    if (v2 > best) { best = v2; arg = 2; }
    if (v3 > best) { best = v3; arg = 3; }
    bp[t - 1][l] = (unsigned char)arg;
    score = best + em[((size_t)b * SEQ + t) * 4 + j];
  }
  score += endw[j];
  float f0 = __shfl(score, b * 4 + 0, 64);
  float f1 = __shfl(score, b * 4 + 1, 64);
  float f2 = __shfl(score, b * 4 + 2, 64);
  float f3 = __shfl(score, b * 4 + 3, 64);
  if (j == 0) {
    float bbv = f0; int last = 0;
    if (f1 > bbv) { bbv = f1; last = 1; }
    if (f2 > bbv) { bbv = f2; last = 2; }
    if (f3 > bbv) { bbv = f3; last = 3; }
    int tag = last;
    out[b * SEQ + (SEQ - 1)] = (float)tag;
    for (int t = SEQ - 2; t >= 0; t--) {
      tag = bp[t][b * 4 + tag];
      out[b * SEQ + t] = (float)tag;
    }
  }
}

// ------------------------------------------------------------------ launcher
extern "C" void kernel_launch(void* const* d_in, const int* in_sizes, int n_in,
                              void* d_out, int out_size, void* d_ws, size_t ws_size,
                              hipStream_t stream) {
  const float* emb      = (const float*)d_in[0];
  const float* l1f_wih  = (const float*)d_in[1];
  const float* l1f_whh  = (const float*)d_in[2];
  const float* l1f_b    = (const float*)d_in[3];
  const float* l1r_wih  = (const float*)d_in[4];
  const float* l1r_whh  = (const float*)d_in[5];
  const float* l1r_b    = (const float*)d_in[6];
  const float* attn_w   = (const float*)d_in[7];
  const float* attn_b   = (const float*)d_in[8];
  const float* l2f_wih  = (const float*)d_in[9];
  const float* l2f_whh  = (const float*)d_in[10];
  const float* l2f_b    = (const float*)d_in[11];
  const float* l2r_wih  = (const float*)d_in[12];
  const float* l2r_whh  = (const float*)d_in[13];
  const float* l2r_b    = (const float*)d_in[14];
  const float* crf_start= (const float*)d_in[15];
  const float* crf_end  = (const float*)d_in[16];
  const float* crf_trans= (const float*)d_in[17];

  float* ws = (float*)d_ws;
  const size_t NCH = (size_t)BATCH * CHUNK * G4;     // 3,145,728 floats
  float* xs_f = ws;
  float* xs_r = xs_f + NCH;
  float* hf   = xs_r + NCH;                          // [b][t][HID]
  float* hr   = hf + (size_t)BATCH * SEQ * HID;
  float* hbuf = hr + (size_t)BATCH * SEQ * HID;      // 24,576: [par][dir][b][HID]
  float* cbuf = hbuf + 2 * 2 * BATCH * HID;          // 12,288: [block][48]
  float* h2   = cbuf + 256 * 48;                     // 32,768
  int*   bar  = (int*)(h2 + 2 * BATCH * SEQ * 4);    // 1,024 ints
  float* xs2  = xs_f;                                // overlay (xs dead post-recurrence)
  float* att  = xs_r;                                // overlay
  float* hs   = hf;                                  // after k_sum, hf holds hf+hr
  // total ~48.3 MiB

  k_init<<<dim3(96), dim3(256), 0, stream>>>(hbuf, bar);

  for (int c = 0; c < 4; c++) {
    k_proj1<<<dim3(24, 8, 2), dim3(256), 0, stream>>>(
        emb, l1f_wih, l1f_b, l1r_wih, l1r_b, xs_f, xs_r, c);
    k_rec1<<<dim3(256), dim3(384), 0, stream>>>(
        l1f_whh, l1r_whh, xs_f, xs_r, hbuf, cbuf, bar, hf, hr,
        c * CHUNK, c == 0 ? 1 : 0);
  }

  k_sum<<<dim3(3072), dim3(256), 0, stream>>>(hf, hr);
  k_attn<<<dim3(SEQ, BATCH), dim3(64), 0, stream>>>(hs, attn_w, attn_b, att);
  k_proj2<<<dim3(SEQ, BATCH), dim3(256), 0, stream>>>(
      hs, att, l2f_wih, l2f_b, l2r_wih, l2r_b, xs2);
  k_rec2<<<dim3(1), dim3(256), 0, stream>>>(xs2, l2f_whh, l2r_whh, h2);
  k_em<<<dim3(64), dim3(256), 0, stream>>>(h2, (float*)d_out);
  k_viterbi<<<dim3(1), dim3(32), 0, stream>>>((float*)d_out, crf_start, crf_end, crf_trans);
}

// Round 4
// 5720.819 us; speedup vs baseline: 1.7560x; 1.7560x over previous
//
#include <hip/hip_runtime.h>
#include <math.h>

#define SEQ 512
#define BATCH 8
#define HID 768
#define G4 3072           // 4*HID
#define CHUNK 128
#define NEGV (-1000000000.0f)

typedef float v4f __attribute__((ext_vector_type(4)));

__device__ __forceinline__ float sigm(float x) { return 1.0f / (1.0f + expf(-x)); }

__device__ __forceinline__ float wred(float x) {
#pragma unroll
  for (int off = 32; off > 0; off >>= 1) x += __shfl_xor(x, off, 64);
  return x;
}

// ---- device-coherent (bypass L1+L2) memory ops: always correct cross-XCD ----
__device__ __forceinline__ void load2_f4_sc(const float* p0, const float* p1,
                                            v4f& a, v4f& b) {
  asm volatile("global_load_dwordx4 %0, %2, off sc0 sc1\n\t"
               "global_load_dwordx4 %1, %3, off sc0 sc1\n\t"
               "s_waitcnt vmcnt(0)"
               : "=&v"(a), "=&v"(b) : "v"(p0), "v"(p1) : "memory");
}
__device__ __forceinline__ int load_i_sc(const int* p) {
  int r;
  asm volatile("global_load_dword %0, %1, off sc0 sc1\n\ts_waitcnt vmcnt(0)"
               : "=v"(r) : "v"(p) : "memory");
  return r;
}
__device__ __forceinline__ void store_f_sc(float* p, float v) {
  asm volatile("global_store_dword %0, %1, off sc0 sc1" :: "v"(p), "v"(v) : "memory");
}
__device__ __forceinline__ void store_i_sc(int* p, int v) {
  asm volatile("global_store_dword %0, %1, off sc0 sc1" :: "v"(p), "v"(v) : "memory");
}

// ---- VALU-pipe 32-lane reduction: 4x row_ror (row sums) + row_bcast15 ----
// canonical GCN DPP reduction; after it, all lanes in rows 1,3 (kq>=16)
// hold the full 32-lane sum.
template <int CTRL, int RMASK>
__device__ __forceinline__ float dpp_add(float x) {
  int y = __builtin_amdgcn_update_dpp(0, __float_as_int(x), CTRL, RMASK, 0xF, false);
  return x + __int_as_float(y);
}
__device__ __forceinline__ float reduce32(float x) {
  x = dpp_add<0x121, 0xF>(x);  // row_ror:1
  x = dpp_add<0x122, 0xF>(x);  // row_ror:2
  x = dpp_add<0x124, 0xF>(x);  // row_ror:4
  x = dpp_add<0x128, 0xF>(x);  // row_ror:8  -> every lane holds its 16-row sum
  x = dpp_add<0x142, 0xA>(x);  // row_bcast15 into rows 1,3 -> kq>=16 = 32-sum
  return x;
}

// ---------------------------------------------------------------- init zeros
__global__ void k_init(float* __restrict__ hbuf, int* __restrict__ flags) {
  int i = blockIdx.x * blockDim.x + threadIdx.x;
  if (i < 2 * 2 * BATCH * HID) hbuf[i] = 0.0f;   // [par][dir][b][HID]
  if (i < 256) flags[i] = 0;                     // [grp][jb]
}

// ------------------------------------------- L1 input projection, one chunk
__global__ __launch_bounds__(256) void k_proj1(
    const float* __restrict__ emb,
    const float* __restrict__ w_f, const float* __restrict__ b_f,
    const float* __restrict__ w_r, const float* __restrict__ b_r,
    float* __restrict__ xs_f, float* __restrict__ xs_r, int chunk) {
  __shared__ float As[16][132];
  __shared__ float Bs[16][132];
  const int tid = threadIdx.x;
  const int bn0 = blockIdx.x * 128;
  const int bb  = blockIdx.y;
  const int dir = blockIdx.z;
  const float* W    = dir ? w_r : w_f;
  const float* bias = dir ? b_r : b_f;
  float* xs = dir ? xs_r : xs_f;

  float acc[8][8];
#pragma unroll
  for (int i = 0; i < 8; i++)
#pragma unroll
    for (int j = 0; j < 8; j++) acc[i][j] = 0.0f;

  const int mload = tid & 127;
  const int kq0   = tid >> 7;
  const int tglob = dir ? (SEQ - 1 - (chunk * CHUNK + mload)) : (chunk * CHUNK + mload);
  const float* arow = emb + (size_t)(bb * SEQ + tglob) * HID;
  const float* brow = W + (size_t)(bn0 + mload) * HID;
  const int tm = tid & 15, tn = tid >> 4;

  for (int kt = 0; kt < HID; kt += 16) {
#pragma unroll
    for (int rep = 0; rep < 2; rep++) {
      int kq = kq0 + rep * 2;
      float4 a = *(const float4*)(arow + kt + kq * 4);
      As[kq * 4 + 0][mload] = a.x; As[kq * 4 + 1][mload] = a.y;
      As[kq * 4 + 2][mload] = a.z; As[kq * 4 + 3][mload] = a.w;
      float4 b = *(const float4*)(brow + kt + kq * 4);
      Bs[kq * 4 + 0][mload] = b.x; Bs[kq * 4 + 1][mload] = b.y;
      Bs[kq * 4 + 2][mload] = b.z; Bs[kq * 4 + 3][mload] = b.w;
    }
    __syncthreads();
#pragma unroll
    for (int k = 0; k < 16; k++) {
      float4 a0 = *(const float4*)&As[k][tm * 8];
      float4 a1 = *(const float4*)&As[k][tm * 8 + 4];
      float4 b0 = *(const float4*)&Bs[k][tn * 8];
      float4 b1 = *(const float4*)&Bs[k][tn * 8 + 4];
      float av[8] = {a0.x, a0.y, a0.z, a0.w, a1.x, a1.y, a1.z, a1.w};
      float bv[8] = {b0.x, b0.y, b0.z, b0.w, b1.x, b1.y, b1.z, b1.w};
#pragma unroll
      for (int i = 0; i < 8; i++)
#pragma unroll
        for (int j = 0; j < 8; j++) acc[i][j] += av[i] * bv[j];
    }
    __syncthreads();
  }
#pragma unroll
  for (int i = 0; i < 8; i++) {
    int row = tm * 8 + i;
    size_t base = (size_t)(bb * CHUNK + row) * G4 + bn0 + tn * 8;
#pragma unroll
    for (int j = 0; j < 8; j++) xs[base + j] = acc[i][j] + bias[bn0 + tn * 8 + j];
  }
}

// ---------------------------------------- L1 recurrence: persistent kernel
// 256 blocks x 384 threads, 1 block/CU (LDS filler). Block = (dir, b-half,
// 12 j's). Thread (g in 12, kq in 32) holds W_hh[4 gates][interleaved 24 k]
// in 96 VGPRs; k-slice = {q*128 + kq*4 + 0..3, q<6} -> conflict-optimal
// ds_read_b128 (32 lanes cover all 32 banks). Flag sync, sc0sc1 exchange.
__global__ __launch_bounds__(384, 2) void k_rec1(
    const float* __restrict__ whh_f, const float* __restrict__ whh_r,
    const float* __restrict__ xs_f, const float* __restrict__ xs_r,
    float* __restrict__ hbuf, float* __restrict__ cbuf, int* __restrict__ flags,
    float* __restrict__ hf, float* __restrict__ hr, int t0, int init) {
  __shared__ float hlds[4 * HID];   // 12,288 B static (+73,728 B dynamic filler)
  const int tid = threadIdx.x;
  const int bid = blockIdx.x;
  const int dir = bid >> 7;
  const int bh  = (bid >> 6) & 1;
  const int jb  = bid & 63;
  const int J0  = jb * 12;
  const int grp = dir * 2 + bh;
  const int g  = tid >> 5;
  const int kq = tid & 31;
  const int j  = J0 + g;

  const float* W  = dir ? whh_r : whh_f;
  const float* xs = dir ? xs_r  : xs_f;
  float* harr = dir ? hr : hf;

  // W_hh slice -> registers (once per chunk launch), interleaved k layout
  float wreg[4][24];
#pragma unroll
  for (int gate = 0; gate < 4; gate++) {
#pragma unroll
    for (int q = 0; q < 6; q++) {
      *(v4f*)&wreg[gate][q * 4] =
          *(const v4f*)&W[(size_t)(gate * HID + j) * HID + q * 128 + kq * 4];
    }
  }

  float cc[4];
#pragma unroll
  for (int b = 0; b < 4; b++) cc[b] = 0.0f;
  if (!init && kq == 16) {
#pragma unroll
    for (int b = 0; b < 4; b++) cc[b] = cbuf[bid * 48 + g * 4 + b];
  }

  for (int stp = 0; stp < CHUNK; stp++) {
    const int s = t0 + stp;
    const int par = s & 1;

    // wait until all 64 blocks of this group published h_{s-1}
    if (tid < 64) {
      const int* fp = flags + grp * 64 + tid;
      while (load_i_sc(fp) < s) { }
    }
    __syncthreads();

    // stage h_{s-1} (my dir, my 4 b's) into LDS
    {
      const float* src = hbuf + (size_t)((par * 2 + dir) * BATCH + bh * 4) * HID + tid * 8;
      v4f a, b4;
      load2_f4_sc(src, src + 4, a, b4);
      *(v4f*)&hlds[tid * 8]     = a;
      *(v4f*)&hlds[tid * 8 + 4] = b4;
    }
    __syncthreads();

    // dots: 4 gates x 4 b over this thread's interleaved k-slice
    float acc[4][4];
#pragma unroll
    for (int gate = 0; gate < 4; gate++)
#pragma unroll
      for (int b = 0; b < 4; b++) acc[gate][b] = 0.0f;
#pragma unroll
    for (int b = 0; b < 4; b++) {
      float hk[24];
#pragma unroll
      for (int q = 0; q < 6; q++)
        *(v4f*)&hk[q * 4] = *(const v4f*)&hlds[b * HID + q * 128 + kq * 4];
#pragma unroll
      for (int gate = 0; gate < 4; gate++)
#pragma unroll
        for (int k = 0; k < 24; k++) acc[gate][b] += wreg[gate][k] * hk[k];
    }
#pragma unroll
    for (int gate = 0; gate < 4; gate++)
#pragma unroll
      for (int b = 0; b < 4; b++) acc[gate][b] = reduce32(acc[gate][b]);

    // writers: LSTM pointwise + publish h
    if (kq == 16) {
      const int t = dir ? (SEQ - 1 - s) : s;
#pragma unroll
      for (int b = 0; b < 4; b++) {
        const int bg = bh * 4 + b;
        const size_t xbase = (size_t)(bg * CHUNK + stp) * G4 + j;
        float iv = acc[0][b] + xs[xbase + 0 * HID];
        float fv = acc[1][b] + xs[xbase + 1 * HID];
        float gv = acc[2][b] + xs[xbase + 2 * HID];
        float ov = acc[3][b] + xs[xbase + 3 * HID];
        cc[b] = sigm(fv) * cc[b] + sigm(iv) * tanhf(gv);
        float h = sigm(ov) * tanhf(cc[b]);
        store_f_sc(hbuf + (size_t)(((par ^ 1) * 2 + dir) * BATCH + bg) * HID + j, h);
        harr[(size_t)(bg * SEQ + t) * HID + j] = h;
      }
    }
    asm volatile("s_waitcnt vmcnt(0)" ::: "memory");
    __syncthreads();
    if (tid == 0) store_i_sc(flags + grp * 64 + jb, s + 1);
  }
  if (kq == 16) {
#pragma unroll
    for (int b = 0; b < 4; b++) cbuf[bid * 48 + g * 4 + b] = cc[b];
  }
}

// ----------------------------------------------------------- hs = hf + hr
__global__ void k_sum(float* __restrict__ hf, const float* __restrict__ hr) {
  int i = blockIdx.x * 256 + threadIdx.x;
  float4 a = ((const float4*)hf)[i];
  float4 b = ((const float4*)hr)[i];
  a.x += b.x; a.y += b.y; a.z += b.z; a.w += b.w;
  ((float4*)hf)[i] = a;
}

// --------------------------------------------------------- windowed attention
__global__ __launch_bounds__(64) void k_attn(
    const float* __restrict__ hs, const float* __restrict__ attn_w,
    const float* __restrict__ attn_b, float* __restrict__ att) {
  const int l = threadIdx.x;
  const int s = blockIdx.x, b = blockIdx.y;
  const float* hrow = hs + (size_t)(b * SEQ + s) * HID;
  float v[12];
  float u1p = 0.0f;
#pragma unroll
  for (int jj = 0; jj < 12; jj++) {
    int d = l + 64 * jj;
    float x = hrow[d];
    u1p += x * attn_w[d];
    v[jj] = attn_w[HID + d] + x * attn_w[2 * HID + d];
  }
  float u1 = wred(u1p) + attn_b[0];
  float sc[21];
  for (int o = 0; o < 21; o++) {
    int s2 = s + o - 10;
    if (s2 >= 0 && s2 < SEQ) {
      const float* h2 = hs + (size_t)(b * SEQ + s2) * HID;
      float p = 0.0f;
#pragma unroll
      for (int jj = 0; jj < 12; jj++) p += h2[l + 64 * jj] * v[jj];
      sc[o] = wred(p) + u1;
    } else {
      sc[o] = NEGV;
    }
  }
  float m = sc[0];
#pragma unroll
  for (int o = 1; o < 21; o++) m = fmaxf(m, sc[o]);
  float sum = 0.0f;
#pragma unroll
  for (int o = 0; o < 21; o++) { sc[o] = expf(sc[o] - m); sum += sc[o]; }
  float inv = 1.0f / sum;
  float acc[12];
#pragma unroll
  for (int jj = 0; jj < 12; jj++) acc[jj] = 0.0f;
  for (int o = 0; o < 21; o++) {
    int s2 = s + o - 10;
    if (s2 < 0 || s2 >= SEQ) continue;
    float a = sc[o] * inv;
    const float* h2 = hs + (size_t)(b * SEQ + s2) * HID;
#pragma unroll
    for (int jj = 0; jj < 12; jj++) acc[jj] += a * h2[l + 64 * jj];
  }
  float* orow = att + (size_t)(b * SEQ + s) * HID;
#pragma unroll
  for (int jj = 0; jj < 12; jj++) orow[l + 64 * jj] = acc[jj];
}

// -------------------------------------------------------- L2 input projection
__global__ __launch_bounds__(256) void k_proj2(
    const float* __restrict__ hs, const float* __restrict__ att,
    const float* __restrict__ w2f, const float* __restrict__ b2f,
    const float* __restrict__ w2r, const float* __restrict__ b2r,
    float* __restrict__ xs2) {
  __shared__ __align__(16) float x2[2 * HID];
  __shared__ float part[32][9];
  const int tid = threadIdx.x;
  const int s = blockIdx.x, b = blockIdx.y;
  size_t base = (size_t)(b * SEQ + s) * HID;
  for (int i = tid; i < 2 * HID; i += 256)
    x2[i] = (i < HID) ? hs[base + i] : att[base + i - HID];
  __syncthreads();
  const int gid = tid & 31, pp = tid >> 5;
  const int d = gid >> 4, g = gid & 15;
  const float4* w4 = (const float4*)((d ? w2r : w2f) + (size_t)g * (2 * HID));
  const float4* x4 = (const float4*)x2;
  float p = 0.0f;
  for (int e = pp * 48; e < pp * 48 + 48; e++) {
    float4 xv = x4[e];
    float4 wv = w4[e];
    p += xv.x * wv.x + xv.y * wv.y + xv.z * wv.z + xv.w * wv.w;
  }
  part[gid][pp] = p;
  __syncthreads();
  if (tid < 32) {
    float sumv = (d ? b2r : b2f)[g];
#pragma unroll
    for (int q = 0; q < 8; q++) sumv += part[gid][q];
    xs2[(size_t)((d * BATCH + b) * SEQ + s) * 16 + g] = sumv;
  }
}

// ------------------------------------------------------------- L2 recurrence
__global__ __launch_bounds__(256) void k_rec2(
    const float* __restrict__ xs2,
    const float* __restrict__ whh_f, const float* __restrict__ whh_r,
    float* __restrict__ h2) {
  __shared__ float hsh[2 * BATCH * 4];
  __shared__ float gsh[2 * BATCH * 16];
  const int tid = threadIdx.x;
  const int d = tid >> 7, b = (tid >> 4) & 7, g = tid & 15;
  const float* whh = (d ? whh_r : whh_f) + g * 4;
  const float w0 = whh[0], w1 = whh[1], w2 = whh[2], w3 = whh[3];
  const int hb = d * BATCH + b;
  if (g < 4) hsh[hb * 4 + g] = 0.0f;
  float c = 0.0f;
  __syncthreads();
  const float* xrow = xs2 + (size_t)hb * SEQ * 16 + g;
  for (int st = 0; st < SEQ; st++) {
    int t = d ? (SEQ - 1 - st) : st;
    float gv = xrow[t * 16] + w0 * hsh[hb * 4 + 0] + w1 * hsh[hb * 4 + 1] +
               w2 * hsh[hb * 4 + 2] + w3 * hsh[hb * 4 + 3];
    gsh[hb * 16 + g] = gv;
    __syncthreads();
    if (g < 4) {
      float iv = gsh[hb * 16 + g];
      float fv = gsh[hb * 16 + 4 + g];
      float gq = gsh[hb * 16 + 8 + g];
      float ov = gsh[hb * 16 + 12 + g];
      c = sigm(fv) * c + sigm(iv) * tanhf(gq);
      float h = sigm(ov) * tanhf(c);
      hsh[hb * 4 + g] = h;
      h2[((size_t)hb * SEQ + t) * 4 + g] = h;
    }
    __syncthreads();
  }
}

// ------------------------------------------------------------------ em = f+r
__global__ void k_em(const float* __restrict__ h2, float* __restrict__ out) {
  int i = blockIdx.x * 256 + threadIdx.x;
  if (i < BATCH * SEQ * 4) out[BATCH * SEQ + i] = h2[i] + h2[BATCH * SEQ * 4 + i];
}

// ------------------------------------------------------------------- viterbi
__global__ __launch_bounds__(32) void k_viterbi(
    float* __restrict__ out, const float* __restrict__ start,
    const float* __restrict__ endw, const float* __restrict__ trans) {
  __shared__ unsigned char bp[SEQ - 1][32];
  const int l = threadIdx.x;
  const int b = l >> 2, j = l & 3;
  const float* em = out + BATCH * SEQ;
  const float tr0 = trans[0 * 4 + j], tr1 = trans[1 * 4 + j];
  const float tr2 = trans[2 * 4 + j], tr3 = trans[3 * 4 + j];
  float score = start[j] + em[((size_t)b * SEQ + 0) * 4 + j];
  for (int t = 1; t < SEQ; t++) {
    float s0 = __shfl(score, b * 4 + 0, 64);
    float s1 = __shfl(score, b * 4 + 1, 64);
    float s2 = __shfl(score, b * 4 + 2, 64);
    float s3 = __shfl(score, b * 4 + 3, 64);
    float v0 = s0 + tr0, v1 = s1 + tr1, v2 = s2 + tr2, v3 = s3 + tr3;
    float best = v0; int arg = 0;
    if (v1 > best) { best = v1; arg = 1; }
    if (v2 > best) { best = v2; arg = 2; }
    if (v3 > best) { best = v3; arg = 3; }
    bp[t - 1][l] = (unsigned char)arg;
    score = best + em[((size_t)b * SEQ + t) * 4 + j];
  }
  score += endw[j];
  float f0 = __shfl(score, b * 4 + 0, 64);
  float f1 = __shfl(score, b * 4 + 1, 64);
  float f2 = __shfl(score, b * 4 + 2, 64);
  float f3 = __shfl(score, b * 4 + 3, 64);
  if (j == 0) {
    float bbv = f0; int last = 0;
    if (f1 > bbv) { bbv = f1; last = 1; }
    if (f2 > bbv) { bbv = f2; last = 2; }
    if (f3 > bbv) { bbv = f3; last = 3; }
    int tag = last;
    out[b * SEQ + (SEQ - 1)] = (float)tag;
    for (int t = SEQ - 2; t >= 0; t--) {
      tag = bp[t][b * 4 + tag];
      out[b * SEQ + t] = (float)tag;
    }
  }
}

// ------------------------------------------------------------------ launcher
extern "C" void kernel_launch(void* const* d_in, const int* in_sizes, int n_in,
                              void* d_out, int out_size, void* d_ws, size_t ws_size,
                              hipStream_t stream) {
  const float* emb      = (const float*)d_in[0];
  const float* l1f_wih  = (const float*)d_in[1];
  const float* l1f_whh  = (const float*)d_in[2];
  const float* l1f_b    = (const float*)d_in[3];
  const float* l1r_wih  = (const float*)d_in[4];
  const float* l1r_whh  = (const float*)d_in[5];
  const float* l1r_b    = (const float*)d_in[6];
  const float* attn_w   = (const float*)d_in[7];
  const float* attn_b   = (const float*)d_in[8];
  const float* l2f_wih  = (const float*)d_in[9];
  const float* l2f_whh  = (const float*)d_in[10];
  const float* l2f_b    = (const float*)d_in[11];
  const float* l2r_wih  = (const float*)d_in[12];
  const float* l2r_whh  = (const float*)d_in[13];
  const float* l2r_b    = (const float*)d_in[14];
  const float* crf_start= (const float*)d_in[15];
  const float* crf_end  = (const float*)d_in[16];
  const float* crf_trans= (const float*)d_in[17];

  float* ws = (float*)d_ws;
  const size_t NCH = (size_t)BATCH * CHUNK * G4;     // 3,145,728 floats
  float* xs_f = ws;
  float* xs_r = xs_f + NCH;
  float* hf   = xs_r + NCH;                          // [b][t][HID]
  float* hr   = hf + (size_t)BATCH * SEQ * HID;
  float* hbuf = hr + (size_t)BATCH * SEQ * HID;      // 24,576 floats
  float* cbuf = hbuf + 2 * 2 * BATCH * HID;          // 12,288 floats
  float* h2   = cbuf + 256 * 48;                     // 32,768 floats
  int*   flags= (int*)(h2 + 2 * BATCH * SEQ * 4);    // 256 ints
  float* xs2  = xs_f;                                // overlay
  float* att  = xs_r;                                // overlay
  float* hs   = hf;                                  // after k_sum, hf = hf+hr

  k_init<<<dim3(96), dim3(256), 0, stream>>>(hbuf, flags);

  for (int c = 0; c < 4; c++) {
    k_proj1<<<dim3(24, 8, 2), dim3(256), 0, stream>>>(
        emb, l1f_wih, l1f_b, l1r_wih, l1r_b, xs_f, xs_r, c);
    // 72KB dynamic LDS filler forces 1 block/CU -> even block->CU mapping
    k_rec1<<<dim3(256), dim3(384), 73728, stream>>>(
        l1f_whh, l1r_whh, xs_f, xs_r, hbuf, cbuf, flags, hf, hr,
        c * CHUNK, c == 0 ? 1 : 0);
  }

  k_sum<<<dim3(3072), dim3(256), 0, stream>>>(hf, hr);
  k_attn<<<dim3(SEQ, BATCH), dim3(64), 0, stream>>>(hs, attn_w, attn_b, att);
  k_proj2<<<dim3(SEQ, BATCH), dim3(256), 0, stream>>>(
      hs, att, l2f_wih, l2f_b, l2r_wih, l2r_b, xs2);
  k_rec2<<<dim3(1), dim3(256), 0, stream>>>(xs2, l2f_whh, l2r_whh, h2);
  k_em<<<dim3(64), dim3(256), 0, stream>>>(h2, (float*)d_out);
  k_viterbi<<<dim3(1), dim3(32), 0, stream>>>((float*)d_out, crf_start, crf_end, crf_trans);
}

// Round 5
// 3892.283 us; speedup vs baseline: 2.5810x; 1.4698x over previous
//
#include <hip/hip_runtime.h>
#include <math.h>

#define SEQ 512
#define BATCH 8
#define HID 768
#define G4 3072           // 4*HID
#define CHUNK 128
#define NEGV (-1000000000.0f)

typedef float v4f __attribute__((ext_vector_type(4)));

__device__ __forceinline__ float sigm(float x) { return 1.0f / (1.0f + expf(-x)); }

__device__ __forceinline__ float wred(float x) {
#pragma unroll
  for (int off = 32; off > 0; off >>= 1) x += __shfl_xor(x, off, 64);
  return x;
}

// ---- device-coherent (bypass L1+L2) memory ops: always correct cross-XCD ----
__device__ __forceinline__ void load2_f4_sc(const float* p0, const float* p1,
                                            v4f& a, v4f& b) {
  asm volatile("global_load_dwordx4 %0, %2, off sc0 sc1\n\t"
               "global_load_dwordx4 %1, %3, off sc0 sc1\n\t"
               "s_waitcnt vmcnt(0)"
               : "=&v"(a), "=&v"(b) : "v"(p0), "v"(p1) : "memory");
}
__device__ __forceinline__ int load_i_sc(const int* p) {
  int r;
  asm volatile("global_load_dword %0, %1, off sc0 sc1\n\ts_waitcnt vmcnt(0)"
               : "=v"(r) : "v"(p) : "memory");
  return r;
}
__device__ __forceinline__ void store_f_sc(float* p, float v) {
  asm volatile("global_store_dword %0, %1, off sc0 sc1" :: "v"(p), "v"(v) : "memory");
}
__device__ __forceinline__ void store_i_sc(int* p, int v) {
  asm volatile("global_store_dword %0, %1, off sc0 sc1" :: "v"(p), "v"(v) : "memory");
}

// ---- VALU-pipe 32-lane reduction: 4x row_ror (row sums) + row_bcast15 ----
template <int CTRL, int RMASK>
__device__ __forceinline__ float dpp_add(float x) {
  int y = __builtin_amdgcn_update_dpp(0, __float_as_int(x), CTRL, RMASK, 0xF, false);
  return x + __int_as_float(y);
}
__device__ __forceinline__ float reduce32(float x) {
  x = dpp_add<0x121, 0xF>(x);  // row_ror:1
  x = dpp_add<0x122, 0xF>(x);  // row_ror:2
  x = dpp_add<0x124, 0xF>(x);  // row_ror:4
  x = dpp_add<0x128, 0xF>(x);  // row_ror:8  -> every lane holds its 16-row sum
  x = dpp_add<0x142, 0xA>(x);  // row_bcast15 into rows 1,3 -> kq>=16 = 32-sum
  return x;
}

// ---------------------------------------------------------------- init zeros
// flags are PADDED: one 64B line per flag -> flags[(grp*64+jb)*16]
__global__ void k_init(float* __restrict__ hbuf, int* __restrict__ flags) {
  int i = blockIdx.x * blockDim.x + threadIdx.x;
  if (i < 2 * 2 * BATCH * HID) hbuf[i] = 0.0f;   // [par][dir][b][HID]
  if (i < 4096) flags[i] = 0;                    // 256 flags x 16-int pad
}

// ------------------------------------------- L1 input projection, one chunk
__global__ __launch_bounds__(256) void k_proj1(
    const float* __restrict__ emb,
    const float* __restrict__ w_f, const float* __restrict__ b_f,
    const float* __restrict__ w_r, const float* __restrict__ b_r,
    float* __restrict__ xs_f, float* __restrict__ xs_r, int chunk) {
  __shared__ float As[16][132];
  __shared__ float Bs[16][132];
  const int tid = threadIdx.x;
  const int bn0 = blockIdx.x * 128;
  const int bb  = blockIdx.y;
  const int dir = blockIdx.z;
  const float* W    = dir ? w_r : w_f;
  const float* bias = dir ? b_r : b_f;
  float* xs = dir ? xs_r : xs_f;

  float acc[8][8];
#pragma unroll
  for (int i = 0; i < 8; i++)
#pragma unroll
    for (int j = 0; j < 8; j++) acc[i][j] = 0.0f;

  const int mload = tid & 127;
  const int kq0   = tid >> 7;
  const int tglob = dir ? (SEQ - 1 - (chunk * CHUNK + mload)) : (chunk * CHUNK + mload);
  const float* arow = emb + (size_t)(bb * SEQ + tglob) * HID;
  const float* brow = W + (size_t)(bn0 + mload) * HID;
  const int tm = tid & 15, tn = tid >> 4;

  for (int kt = 0; kt < HID; kt += 16) {
#pragma unroll
    for (int rep = 0; rep < 2; rep++) {
      int kq = kq0 + rep * 2;
      float4 a = *(const float4*)(arow + kt + kq * 4);
      As[kq * 4 + 0][mload] = a.x; As[kq * 4 + 1][mload] = a.y;
      As[kq * 4 + 2][mload] = a.z; As[kq * 4 + 3][mload] = a.w;
      float4 b = *(const float4*)(brow + kt + kq * 4);
      Bs[kq * 4 + 0][mload] = b.x; Bs[kq * 4 + 1][mload] = b.y;
      Bs[kq * 4 + 2][mload] = b.z; Bs[kq * 4 + 3][mload] = b.w;
    }
    __syncthreads();
#pragma unroll
    for (int k = 0; k < 16; k++) {
      float4 a0 = *(const float4*)&As[k][tm * 8];
      float4 a1 = *(const float4*)&As[k][tm * 8 + 4];
      float4 b0 = *(const float4*)&Bs[k][tn * 8];
      float4 b1 = *(const float4*)&Bs[k][tn * 8 + 4];
      float av[8] = {a0.x, a0.y, a0.z, a0.w, a1.x, a1.y, a1.z, a1.w};
      float bv[8] = {b0.x, b0.y, b0.z, b0.w, b1.x, b1.y, b1.z, b1.w};
#pragma unroll
      for (int i = 0; i < 8; i++)
#pragma unroll
        for (int j = 0; j < 8; j++) acc[i][j] += av[i] * bv[j];
    }
    __syncthreads();
  }
#pragma unroll
  for (int i = 0; i < 8; i++) {
    int row = tm * 8 + i;
    size_t base = (size_t)(bb * CHUNK + row) * G4 + bn0 + tn * 8;
#pragma unroll
    for (int j = 0; j < 8; j++) xs[base + j] = acc[i][j] + bias[bn0 + tn * 8 + j];
  }
}

// ---------------------------------------- L1 recurrence: persistent kernel
// 256 blocks x 384 threads. Block = (dir, b-half, 12 j's). Thread (g,kq)
// holds W_hh[4 gates][interleaved 24 k] in 96 VGPRs. Flag sync: one 64B
// line per flag + s_sleep backoff (kills coherence-point queueing).
__global__ __launch_bounds__(384, 2) void k_rec1(
    const float* __restrict__ whh_f, const float* __restrict__ whh_r,
    const float* __restrict__ xs_f, const float* __restrict__ xs_r,
    float* __restrict__ hbuf, float* __restrict__ cbuf, int* __restrict__ flags,
    float* __restrict__ hf, float* __restrict__ hr, int t0, int init) {
  __shared__ float hlds[4 * HID];
  const int tid = threadIdx.x;
  const int bid = blockIdx.x;
  const int dir = bid >> 7;
  const int bh  = (bid >> 6) & 1;
  const int jb  = bid & 63;
  const int J0  = jb * 12;
  const int grp = dir * 2 + bh;
  const int g  = tid >> 5;
  const int kq = tid & 31;
  const int j  = J0 + g;

  const float* W  = dir ? whh_r : whh_f;
  const float* xs = dir ? xs_r  : xs_f;
  float* harr = dir ? hr : hf;

  // W_hh slice -> registers (once per chunk launch), interleaved k layout
  float wreg[4][24];
#pragma unroll
  for (int gate = 0; gate < 4; gate++) {
#pragma unroll
    for (int q = 0; q < 6; q++) {
      *(v4f*)&wreg[gate][q * 4] =
          *(const v4f*)&W[(size_t)(gate * HID + j) * HID + q * 128 + kq * 4];
    }
  }

  float cc[4];
#pragma unroll
  for (int b = 0; b < 4; b++) cc[b] = 0.0f;
  if (!init && kq == 16) {
#pragma unroll
    for (int b = 0; b < 4; b++) cc[b] = cbuf[bid * 48 + g * 4 + b];
  }

  for (int stp = 0; stp < CHUNK; stp++) {
    const int s = t0 + stp;
    const int par = s & 1;

    // prefetch xs gate values for writers BEFORE the wait (cached loads;
    // cannot sink past the asm memory clobbers in the poll loop)
    float xsv[4][4];
    if (kq == 16) {
#pragma unroll
      for (int b = 0; b < 4; b++) {
        const size_t xbase = (size_t)((bh * 4 + b) * CHUNK + stp) * G4 + j;
#pragma unroll
        for (int gate = 0; gate < 4; gate++)
          xsv[b][gate] = xs[xbase + gate * HID];
      }
    }

    // wait until all 64 blocks of this group published h_{s-1}
    if (tid < 64) {
      const int* fp = flags + (grp * 64 + tid) * 16;   // one line per flag
      while (load_i_sc(fp) < s) { __builtin_amdgcn_s_sleep(4); }
    }
    __syncthreads();

    // stage h_{s-1} (my dir, my 4 b's) into LDS
    {
      const float* src = hbuf + (size_t)((par * 2 + dir) * BATCH + bh * 4) * HID + tid * 8;
      v4f a, b4;
      load2_f4_sc(src, src + 4, a, b4);
      *(v4f*)&hlds[tid * 8]     = a;
      *(v4f*)&hlds[tid * 8 + 4] = b4;
    }
    __syncthreads();

    // dots: 4 gates x 4 b over this thread's interleaved k-slice
    float acc[4][4];
#pragma unroll
    for (int gate = 0; gate < 4; gate++)
#pragma unroll
      for (int b = 0; b < 4; b++) acc[gate][b] = 0.0f;
#pragma unroll
    for (int b = 0; b < 4; b++) {
      float hk[24];
#pragma unroll
      for (int q = 0; q < 6; q++)
        *(v4f*)&hk[q * 4] = *(const v4f*)&hlds[b * HID + q * 128 + kq * 4];
#pragma unroll
      for (int gate = 0; gate < 4; gate++)
#pragma unroll
        for (int k = 0; k < 24; k++) acc[gate][b] += wreg[gate][k] * hk[k];
    }
#pragma unroll
    for (int gate = 0; gate < 4; gate++)
#pragma unroll
      for (int b = 0; b < 4; b++) acc[gate][b] = reduce32(acc[gate][b]);

    // writers: LSTM pointwise + publish h
    if (kq == 16) {
      const int t = dir ? (SEQ - 1 - s) : s;
#pragma unroll
      for (int b = 0; b < 4; b++) {
        const int bg = bh * 4 + b;
        float iv = acc[0][b] + xsv[b][0];
        float fv = acc[1][b] + xsv[b][1];
        float gv = acc[2][b] + xsv[b][2];
        float ov = acc[3][b] + xsv[b][3];
        cc[b] = sigm(fv) * cc[b] + sigm(iv) * tanhf(gv);
        float h = sigm(ov) * tanhf(cc[b]);
        store_f_sc(hbuf + (size_t)(((par ^ 1) * 2 + dir) * BATCH + bg) * HID + j, h);
        harr[(size_t)(bg * SEQ + t) * HID + j] = h;
      }
    }
    asm volatile("s_waitcnt vmcnt(0)" ::: "memory");
    __syncthreads();
    if (tid == 0) store_i_sc(flags + (grp * 64 + jb) * 16, s + 1);
  }
  if (kq == 16) {
#pragma unroll
    for (int b = 0; b < 4; b++) cbuf[bid * 48 + g * 4 + b] = cc[b];
  }
}

// ----------------------------------------------------------- hs = hf + hr
__global__ void k_sum(float* __restrict__ hf, const float* __restrict__ hr) {
  int i = blockIdx.x * 256 + threadIdx.x;
  float4 a = ((const float4*)hf)[i];
  float4 b = ((const float4*)hr)[i];
  a.x += b.x; a.y += b.y; a.z += b.z; a.w += b.w;
  ((float4*)hf)[i] = a;
}

// --------------------------------------------------------- windowed attention
__global__ __launch_bounds__(64) void k_attn(
    const float* __restrict__ hs, const float* __restrict__ attn_w,
    const float* __restrict__ attn_b, float* __restrict__ att) {
  const int l = threadIdx.x;
  const int s = blockIdx.x, b = blockIdx.y;
  const float* hrow = hs + (size_t)(b * SEQ + s) * HID;
  float v[12];
  float u1p = 0.0f;
#pragma unroll
  for (int jj = 0; jj < 12; jj++) {
    int d = l + 64 * jj;
    float x = hrow[d];
    u1p += x * attn_w[d];
    v[jj] = attn_w[HID + d] + x * attn_w[2 * HID + d];
  }
  float u1 = wred(u1p) + attn_b[0];
  float sc[21];
  for (int o = 0; o < 21; o++) {
    int s2 = s + o - 10;
    if (s2 >= 0 && s2 < SEQ) {
      const float* h2 = hs + (size_t)(b * SEQ + s2) * HID;
      float p = 0.0f;
#pragma unroll
      for (int jj = 0; jj < 12; jj++) p += h2[l + 64 * jj] * v[jj];
      sc[o] = wred(p) + u1;
    } else {
      sc[o] = NEGV;
    }
  }
  float m = sc[0];
#pragma unroll
  for (int o = 1; o < 21; o++) m = fmaxf(m, sc[o]);
  float sum = 0.0f;
#pragma unroll
  for (int o = 0; o < 21; o++) { sc[o] = expf(sc[o] - m); sum += sc[o]; }
  float inv = 1.0f / sum;
  float acc[12];
#pragma unroll
  for (int jj = 0; jj < 12; jj++) acc[jj] = 0.0f;
  for (int o = 0; o < 21; o++) {
    int s2 = s + o - 10;
    if (s2 < 0 || s2 >= SEQ) continue;
    float a = sc[o] * inv;
    const float* h2 = hs + (size_t)(b * SEQ + s2) * HID;
#pragma unroll
    for (int jj = 0; jj < 12; jj++) acc[jj] += a * h2[l + 64 * jj];
  }
  float* orow = att + (size_t)(b * SEQ + s) * HID;
#pragma unroll
  for (int jj = 0; jj < 12; jj++) orow[l + 64 * jj] = acc[jj];
}

// -------------------------------------------------------- L2 input projection
__global__ __launch_bounds__(256) void k_proj2(
    const float* __restrict__ hs, const float* __restrict__ att,
    const float* __restrict__ w2f, const float* __restrict__ b2f,
    const float* __restrict__ w2r, const float* __restrict__ b2r,
    float* __restrict__ xs2) {
  __shared__ __align__(16) float x2[2 * HID];
  __shared__ float part[32][9];
  const int tid = threadIdx.x;
  const int s = blockIdx.x, b = blockIdx.y;
  size_t base = (size_t)(b * SEQ + s) * HID;
  for (int i = tid; i < 2 * HID; i += 256)
    x2[i] = (i < HID) ? hs[base + i] : att[base + i - HID];
  __syncthreads();
  const int gid = tid & 31, pp = tid >> 5;
  const int d = gid >> 4, g = gid & 15;
  const float4* w4 = (const float4*)((d ? w2r : w2f) + (size_t)g * (2 * HID));
  const float4* x4 = (const float4*)x2;
  float p = 0.0f;
  for (int e = pp * 48; e < pp * 48 + 48; e++) {
    float4 xv = x4[e];
    float4 wv = w4[e];
    p += xv.x * wv.x + xv.y * wv.y + xv.z * wv.z + xv.w * wv.w;
  }
  part[gid][pp] = p;
  __syncthreads();
  if (tid < 32) {
    float sumv = (d ? b2r : b2f)[g];
#pragma unroll
    for (int q = 0; q < 8; q++) sumv += part[gid][q];
    xs2[(size_t)((d * BATCH + b) * SEQ + s) * 16 + g] = sumv;
  }
}

// ------------------------------------------------------------- L2 recurrence
__global__ __launch_bounds__(256) void k_rec2(
    const float* __restrict__ xs2,
    const float* __restrict__ whh_f, const float* __restrict__ whh_r,
    float* __restrict__ h2) {
  __shared__ float hsh[2 * BATCH * 4];
  __shared__ float gsh[2 * BATCH * 16];
  const int tid = threadIdx.x;
  const int d = tid >> 7, b = (tid >> 4) & 7, g = tid & 15;
  const float* whh = (d ? whh_r : whh_f) + g * 4;
  const float w0 = whh[0], w1 = whh[1], w2 = whh[2], w3 = whh[3];
  const int hb = d * BATCH + b;
  if (g < 4) hsh[hb * 4 + g] = 0.0f;
  float c = 0.0f;
  __syncthreads();
  const float* xrow = xs2 + (size_t)hb * SEQ * 16 + g;
  for (int st = 0; st < SEQ; st++) {
    int t = d ? (SEQ - 1 - st) : st;
    float gv = xrow[t * 16] + w0 * hsh[hb * 4 + 0] + w1 * hsh[hb * 4 + 1] +
               w2 * hsh[hb * 4 + 2] + w3 * hsh[hb * 4 + 3];
    gsh[hb * 16 + g] = gv;
    __syncthreads();
    if (g < 4) {
      float iv = gsh[hb * 16 + g];
      float fv = gsh[hb * 16 + 4 + g];
      float gq = gsh[hb * 16 + 8 + g];
      float ov = gsh[hb * 16 + 12 + g];
      c = sigm(fv) * c + sigm(iv) * tanhf(gq);
      float h = sigm(ov) * tanhf(c);
      hsh[hb * 4 + g] = h;
      h2[((size_t)hb * SEQ + t) * 4 + g] = h;
    }
    __syncthreads();
  }
}

// ------------------------------------------------------------------ em = f+r
__global__ void k_em(const float* __restrict__ h2, float* __restrict__ out) {
  int i = blockIdx.x * 256 + threadIdx.x;
  if (i < BATCH * SEQ * 4) out[BATCH * SEQ + i] = h2[i] + h2[BATCH * SEQ * 4 + i];
}

// ------------------------------------------------------------------- viterbi
__global__ __launch_bounds__(32) void k_viterbi(
    float* __restrict__ out, const float* __restrict__ start,
    const float* __restrict__ endw, const float* __restrict__ trans) {
  __shared__ unsigned char bp[SEQ - 1][32];
  const int l = threadIdx.x;
  const int b = l >> 2, j = l & 3;
  const float* em = out + BATCH * SEQ;
  const float tr0 = trans[0 * 4 + j], tr1 = trans[1 * 4 + j];
  const float tr2 = trans[2 * 4 + j], tr3 = trans[3 * 4 + j];
  float score = start[j] + em[((size_t)b * SEQ + 0) * 4 + j];
  for (int t = 1; t < SEQ; t++) {
    float s0 = __shfl(score, b * 4 + 0, 64);
    float s1 = __shfl(score, b * 4 + 1, 64);
    float s2 = __shfl(score, b * 4 + 2, 64);
    float s3 = __shfl(score, b * 4 + 3, 64);
    float v0 = s0 + tr0, v1 = s1 + tr1, v2 = s2 + tr2, v3 = s3 + tr3;
    float best = v0; int arg = 0;
    if (v1 > best) { best = v1; arg = 1; }
    if (v2 > best) { best = v2; arg = 2; }
    if (v3 > best) { best = v3; arg = 3; }
    bp[t - 1][l] = (unsigned char)arg;
    score = best + em[((size_t)b * SEQ + t) * 4 + j];
  }
  score += endw[j];
  float f0 = __shfl(score, b * 4 + 0, 64);
  float f1 = __shfl(score, b * 4 + 1, 64);
  float f2 = __shfl(score, b * 4 + 2, 64);
  float f3 = __shfl(score, b * 4 + 3, 64);
  if (j == 0) {
    float bbv = f0; int last = 0;
    if (f1 > bbv) { bbv = f1; last = 1; }
    if (f2 > bbv) { bbv = f2; last = 2; }
    if (f3 > bbv) { bbv = f3; last = 3; }
    int tag = last;
    out[b * SEQ + (SEQ - 1)] = (float)tag;
    for (int t = SEQ - 2; t >= 0; t--) {
      tag = bp[t][b * 4 + tag];
      out[b * SEQ + t] = (float)tag;
    }
  }
}

// ------------------------------------------------------------------ launcher
extern "C" void kernel_launch(void* const* d_in, const int* in_sizes, int n_in,
                              void* d_out, int out_size, void* d_ws, size_t ws_size,
                              hipStream_t stream) {
  const float* emb      = (const float*)d_in[0];
  const float* l1f_wih  = (const float*)d_in[1];
  const float* l1f_whh  = (const float*)d_in[2];
  const float* l1f_b    = (const float*)d_in[3];
  const float* l1r_wih  = (const float*)d_in[4];
  const float* l1r_whh  = (const float*)d_in[5];
  const float* l1r_b    = (const float*)d_in[6];
  const float* attn_w   = (const float*)d_in[7];
  const float* attn_b   = (const float*)d_in[8];
  const float* l2f_wih  = (const float*)d_in[9];
  const float* l2f_whh  = (const float*)d_in[10];
  const float* l2f_b    = (const float*)d_in[11];
  const float* l2r_wih  = (const float*)d_in[12];
  const float* l2r_whh  = (const float*)d_in[13];
  const float* l2r_b    = (const float*)d_in[14];
  const float* crf_start= (const float*)d_in[15];
  const float* crf_end  = (const float*)d_in[16];
  const float* crf_trans= (const float*)d_in[17];

  float* ws = (float*)d_ws;
  const size_t NCH = (size_t)BATCH * CHUNK * G4;     // 3,145,728 floats
  float* xs_f = ws;
  float* xs_r = xs_f + NCH;
  float* hf   = xs_r + NCH;                          // [b][t][HID]
  float* hr   = hf + (size_t)BATCH * SEQ * HID;
  float* hbuf = hr + (size_t)BATCH * SEQ * HID;      // 24,576 floats
  float* cbuf = hbuf + 2 * 2 * BATCH * HID;          // 12,288 floats
  float* h2   = cbuf + 256 * 48;                     // 32,768 floats
  int*   flags= (int*)(h2 + 2 * BATCH * SEQ * 4);    // 4,096 ints (padded)
  float* xs2  = xs_f;                                // overlay
  float* att  = xs_r;                                // overlay
  float* hs   = hf;                                  // after k_sum, hf = hf+hr

  k_init<<<dim3(96), dim3(256), 0, stream>>>(hbuf, flags);

  for (int c = 0; c < 4; c++) {
    k_proj1<<<dim3(24, 8, 2), dim3(256), 0, stream>>>(
        emb, l1f_wih, l1f_b, l1r_wih, l1r_b, xs_f, xs_r, c);
    k_rec1<<<dim3(256), dim3(384), 0, stream>>>(
        l1f_whh, l1r_whh, xs_f, xs_r, hbuf, cbuf, flags, hf, hr,
        c * CHUNK, c == 0 ? 1 : 0);
  }

  k_sum<<<dim3(3072), dim3(256), 0, stream>>>(hf, hr);
  k_attn<<<dim3(SEQ, BATCH), dim3(64), 0, stream>>>(hs, attn_w, attn_b, att);
  k_proj2<<<dim3(SEQ, BATCH), dim3(256), 0, stream>>>(
      hs, att, l2f_wih, l2f_b, l2r_wih, l2r_b, xs2);
  k_rec2<<<dim3(1), dim3(256), 0, stream>>>(xs2, l2f_whh, l2r_whh, h2);
  k_em<<<dim3(64), dim3(256), 0, stream>>>(h2, (float*)d_out);
  k_viterbi<<<dim3(1), dim3(32), 0, stream>>>((float*)d_out, crf_start, crf_end, crf_trans);
}